// Round 10
// baseline (196.628 us; speedup 1.0000x reference)
//
#include <hip/hip_runtime.h>
#include <stdint.h>

#define B  8
#define TE 2048
#define TD 256
#define H  128

// ---------- kernel 1: register-tiled GEMM (512 thr, 2r x 4h, float4 k-chunks) ----------
// E written t-tiled: EgT[b][tb][k][tl]  (tb = t>>6, tl = t&63); F row-major [b][j][k].
__global__ __launch_bounds__(512) void proj_kernel(
    const float* __restrict__ enc, const float* __restrict__ dec,
    const float* __restrict__ Wa,  const float* __restrict__ Ua,
    float* __restrict__ EgT, float* __restrict__ Fg) {
  __shared__ float Ls[32 * 132];         // 16.9 KB: E-epilogue transpose only
  const float C2 = 2.8853900817779268f;  // 2*log2(e):  exp(2x) = exp2(C2*x)
  int tid = threadIdx.x;
  int bid = blockIdx.x;
  bool isE = (bid < 512);
  int rbase = (isE ? bid : bid - 512) * 32;
  const float* in = isE ? enc : dec;
  const float* Mg = isE ? Wa : Ua;
  int hq = tid & 31, rq = tid >> 5;      // 16 rq groups x 2 rows = 32 rows
  int h0 = hq * 4, r0 = rq * 2;
  const float* rowp = in + (size_t)(rbase + r0) * H;
  const float* wp = Mg + h0;
  float4 a0{0,0,0,0}, a1{0,0,0,0};
  #pragma unroll 2
  for (int kc = 0; kc < 128; kc += 4) {
    float4 r0v = *(const float4*)(rowp + kc);            // broadcast b128 (uniform/half-wave)
    float4 r1v = *(const float4*)(rowp + H + kc);
    float4 w0 = *(const float4*)(wp + (size_t)(kc + 0) * H);  // coalesced 512 B
    float4 w1 = *(const float4*)(wp + (size_t)(kc + 1) * H);
    float4 w2 = *(const float4*)(wp + (size_t)(kc + 2) * H);
    float4 w3 = *(const float4*)(wp + (size_t)(kc + 3) * H);
    a0.x += r0v.x*w0.x + r0v.y*w1.x + r0v.z*w2.x + r0v.w*w3.x;
    a0.y += r0v.x*w0.y + r0v.y*w1.y + r0v.z*w2.y + r0v.w*w3.y;
    a0.z += r0v.x*w0.z + r0v.y*w1.z + r0v.z*w2.z + r0v.w*w3.z;
    a0.w += r0v.x*w0.w + r0v.y*w1.w + r0v.z*w2.w + r0v.w*w3.w;
    a1.x += r1v.x*w0.x + r1v.y*w1.x + r1v.z*w2.x + r1v.w*w3.x;
    a1.y += r1v.x*w0.y + r1v.y*w1.y + r1v.z*w2.y + r1v.w*w3.y;
    a1.z += r1v.x*w0.z + r1v.y*w1.z + r1v.z*w2.z + r1v.w*w3.z;
    a1.w += r1v.x*w0.w + r1v.y*w1.w + r1v.z*w2.w + r1v.w*w3.w;
  }
  float4 e0, e1;
  e0.x = __builtin_amdgcn_exp2f(a0.x * C2); e0.y = __builtin_amdgcn_exp2f(a0.y * C2);
  e0.z = __builtin_amdgcn_exp2f(a0.z * C2); e0.w = __builtin_amdgcn_exp2f(a0.w * C2);
  e1.x = __builtin_amdgcn_exp2f(a1.x * C2); e1.y = __builtin_amdgcn_exp2f(a1.y * C2);
  e1.z = __builtin_amdgcn_exp2f(a1.z * C2); e1.w = __builtin_amdgcn_exp2f(a1.w * C2);
  if (isE) {
    *(float4*)&Ls[(r0 + 0) * 132 + h0] = e0;
    *(float4*)&Ls[(r0 + 1) * 132 + h0] = e1;
    __syncthreads();
    int b_e = rbase >> 11, t_in = rbase & 2047;
    int tb = t_in >> 6, toff = t_in & 63;                // 32-row block = half a tb tile
    float* dst = EgT + ((size_t)(b_e * 32 + tb) * 128) * 64 + toff;
    #pragma unroll
    for (int jj = 0; jj < 8; ++jj) {                     // 4096 floats
      int idx = jj * 512 + tid;
      int r = idx & 31, k = idx >> 5;
      dst[(size_t)k * 64 + r] = Ls[r * 132 + k];
    }
  } else {
    int b_f = rbase >> 8, j_in = rbase & 255;
    float* dst = Fg + ((size_t)(b_f * TD + j_in + r0)) * H + h0;
    *(float4*)(dst + 0 * H) = e0;
    *(float4*)(dst + 1 * H) = e1;
  }
}

// ---------- kernel 2: fused scores -> softmax -> context ----------
// Block = (b, 4 j-rows, all t). 1024 thr = 16 waves, 33 KB LDS, grid 512 = 2 blocks/CU
// -> 32 waves/CU (100% occupancy window for the rcp-bound phase 1).
__global__ __launch_bounds__(1024) void fused_kernel(
    const float* __restrict__ EgT, const float* __restrict__ Fg,
    const float* __restrict__ Va,  const float* __restrict__ enc,
    float* __restrict__ oute, float* __restrict__ outc) {
  __shared__ float S[4 * 2048];    // 32 KB: scores [j][t] -> e [t][4j] -> c-partials
  __shared__ float red[32];
  int tid = threadIdx.x;
  int jt = blockIdx.x, b = blockIdx.y;
  int j0 = jt * 4;
  int lane = tid & 63, w = tid >> 6;           // 16 waves
  const float4* vp = (const float4*)Va;
  float V1 = 0.f;
  #pragma unroll
  for (int q = 0; q < 32; ++q) { float4 v = vp[q]; V1 += v.x + v.y + v.z + v.w; }

  // ---- phase 1: scores[j][t] into LDS ----
  const float4* Fp = (const float4*)(Fg + (size_t)(b * TD + j0) * H);
  for (int it = 0; it < 2; ++it) {
    int tb = w + 16 * it;                      // 16 waves x 2 iters = 32 tb
    const float* Ep = EgT + ((size_t)(b * 32 + tb) * 128) * 64 + lane;
    float s0 = 0.f, s1 = 0.f, s2 = 0.f, s3 = 0.f;
    for (int kc = 0; kc < 16; ++kc) {          // 8 k per chunk
      const float* ep = Ep + kc * 512;
      float ek[8];
      #pragma unroll
      for (int q = 0; q < 8; ++q) ek[q] = ep[q * 64];   // imm offsets 0..1792 B
      float4 v0 = vp[kc * 2], v1 = vp[kc * 2 + 1];
      const float4* fp = Fp + kc * 2;
      #pragma unroll
      for (int j = 0; j < 4; ++j) {
        float4 f0 = fp[j * 32];
        float4 f1 = fp[j * 32 + 1];
        float a;
        a  = v0.x * __builtin_amdgcn_rcpf(fmaf(ek[0], f0.x, 1.0f));
        a += v0.y * __builtin_amdgcn_rcpf(fmaf(ek[1], f0.y, 1.0f));
        a += v0.z * __builtin_amdgcn_rcpf(fmaf(ek[2], f0.z, 1.0f));
        a += v0.w * __builtin_amdgcn_rcpf(fmaf(ek[3], f0.w, 1.0f));
        a += v1.x * __builtin_amdgcn_rcpf(fmaf(ek[4], f1.x, 1.0f));
        a += v1.y * __builtin_amdgcn_rcpf(fmaf(ek[5], f1.y, 1.0f));
        a += v1.z * __builtin_amdgcn_rcpf(fmaf(ek[6], f1.z, 1.0f));
        a += v1.w * __builtin_amdgcn_rcpf(fmaf(ek[7], f1.w, 1.0f));
        if (j == 0) s0 += a; else if (j == 1) s1 += a; else if (j == 2) s2 += a; else s3 += a;
      }
    }
    int t = tb * 64 + lane;
    S[0 * 2048 + t] = V1 - 2.0f * s0;          // bank = lane%32: 2-way (free)
    S[1 * 2048 + t] = V1 - 2.0f * s1;
    S[2 * 2048 + t] = V1 - 2.0f * s2;
    S[3 * 2048 + t] = V1 - 2.0f * s3;
  }
  __syncthreads();

  // ---- phase 2: softmax per j-row (4 waves per j), e -> d_out + S[t][4j] ----
  int j = w >> 2, quarter = w & 3;
  int tb2 = quarter * 512 + lane;
  float x[8];
  #pragma unroll
  for (int q = 0; q < 8; ++q) x[q] = S[j * 2048 + tb2 + q * 64];
  float m = x[0];
  #pragma unroll
  for (int q = 1; q < 8; ++q) m = fmaxf(m, x[q]);
  #pragma unroll
  for (int off = 32; off > 0; off >>= 1) m = fmaxf(m, __shfl_xor(m, off));
  if (lane == 0) red[w] = m;
  __syncthreads();                             // also: all raw-S reads complete
  m = fmaxf(fmaxf(red[j * 4], red[j * 4 + 1]), fmaxf(red[j * 4 + 2], red[j * 4 + 3]));
  const float L2E = 1.4426950408889634f;
  float sum = 0.f;
  #pragma unroll
  for (int q = 0; q < 8; ++q) {
    x[q] = __builtin_amdgcn_exp2f((x[q] - m) * L2E);
    sum += x[q];
  }
  #pragma unroll
  for (int off = 32; off > 0; off >>= 1) sum += __shfl_xor(sum, off);
  if (lane == 0) red[16 + w] = sum;
  __syncthreads();
  float inv = 1.0f / (red[16 + j * 4] + red[16 + j * 4 + 1] +
                      red[16 + j * 4 + 2] + red[16 + j * 4 + 3]);
  float* orow = oute + (size_t)(b * TD + j0 + j) * TE;
  #pragma unroll
  for (int q = 0; q < 8; ++q) {
    float e = x[q] * inv;
    int t = tb2 + q * 64;
    orow[t] = e;                               // coalesced
    S[t * 4 + j] = e;                          // S re-viewed as [t][4j]
  }
  __syncthreads();

  // ---- phase 3: c[j][h] = sum_t e[j][t]*enc[t][h]; 32 t-slices, 2-round LDS combine ----
  int hq = tid & 31, slice = tid >> 5;         // h = hq*4; t in [slice*64, slice*64+64)
  const float* encp = enc + ((size_t)b * TE + slice * 64) * H + hq * 4;
  float4 acc[4];
  #pragma unroll
  for (int p = 0; p < 4; ++p) acc[p] = float4{0.f, 0.f, 0.f, 0.f};
  #pragma unroll 4
  for (int t = 0; t < 64; ++t) {
    float4 ev = *(const float4*)(encp + (size_t)t * H);          // 2 x 512 B / wave-instr
    float4 e4 = *(const float4*)&S[(slice * 64 + t) * 4];        // 2-addr b128 broadcast
    acc[0].x += e4.x * ev.x; acc[0].y += e4.x * ev.y; acc[0].z += e4.x * ev.z; acc[0].w += e4.x * ev.w;
    acc[1].x += e4.y * ev.x; acc[1].y += e4.y * ev.y; acc[1].z += e4.y * ev.z; acc[1].w += e4.y * ev.w;
    acc[2].x += e4.z * ev.x; acc[2].y += e4.z * ev.y; acc[2].z += e4.z * ev.z; acc[2].w += e4.z * ev.w;
    acc[3].x += e4.w * ev.x; acc[3].y += e4.w * ev.y; acc[3].z += e4.w * ev.z; acc[3].w += e4.w * ev.w;
  }
  __syncthreads();                             // all e-reads done; reuse S for partials
  if (slice >= 16) {                           // round A: high slices write 32 KB of partials
    #pragma unroll
    for (int p = 0; p < 4; ++p)
      *(float4*)&S[(slice - 16) * 512 + p * 128 + hq * 4] = acc[p];
  }
  __syncthreads();
  if (slice < 16) {                            // round B: low slices accumulate in place
    #pragma unroll
    for (int p = 0; p < 4; ++p) {
      float4 cur = *(const float4*)&S[slice * 512 + p * 128 + hq * 4];
      cur.x += acc[p].x; cur.y += acc[p].y; cur.z += acc[p].z; cur.w += acc[p].w;
      *(float4*)&S[slice * 512 + p * 128 + hq * 4] = cur;
    }
  }
  __syncthreads();
  if (tid < 512) {                             // final: 16-way tree over slices
    float r = 0.f;
    #pragma unroll
    for (int sl = 0; sl < 16; ++sl) r += S[sl * 512 + tid];      // stride-1, conflict-free
    outc[(size_t)(b * TD + j0 + (tid >> 7)) * H + (tid & 127)] = r;
  }
}

extern "C" void kernel_launch(void* const* d_in, const int* in_sizes, int n_in,
                              void* d_out, int out_size, void* d_ws, size_t ws_size,
                              hipStream_t stream) {
  (void)in_sizes; (void)n_in; (void)out_size; (void)ws_size;
  const float* enc = (const float*)d_in[0];
  const float* dec = (const float*)d_in[1];
  const float* Wa  = (const float*)d_in[2];
  const float* Ua  = (const float*)d_in[3];
  const float* Va  = (const float*)d_in[4];

  float* ws  = (float*)d_ws;
  float* EgT = ws;                                   // 2,097,152 f32 (8 MB)  E tiled [b][tb][k][tl]
  float* Fg  = EgT + (size_t)B * TE * H;             //   262,144 f32 (1 MB)  F [b][j][k]
  float* outc = (float*)d_out;                       // c [B,TD,H] fp32
  float* oute = outc + (size_t)B * TD * H;           // e [B,TD,TE] fp32

  proj_kernel<<<dim3(576), 512, 0, stream>>>(enc, dec, Wa, Ua, EgT, Fg);
  fused_kernel<<<dim3(64, 8), 1024, 0, stream>>>(EgT, Fg, Va, enc, oute, outc);
}

// Round 11
// 169.821 us; speedup vs baseline: 1.1579x; 1.1579x over previous
//
#include <hip/hip_runtime.h>
#include <stdint.h>

#define B  8
#define TE 2048
#define TD 256
#define H  128

// ---------- kernel 1: register-tiled GEMM (R9-exact: 256 thr, 4r x 4h, b32 row loads) ----------
// E written t-tiled: EgT[b][tb][k][tl]  (tb = t>>6, tl = t&63); F row-major [b][j][k].
__global__ __launch_bounds__(256) void proj_kernel(
    const float* __restrict__ enc, const float* __restrict__ dec,
    const float* __restrict__ Wa,  const float* __restrict__ Ua,
    float* __restrict__ EgT, float* __restrict__ Fg) {
  __shared__ float Ls[32 * 132];         // 16.9 KB: E-epilogue transpose only
  const float C2 = 2.8853900817779268f;  // 2*log2(e):  exp(2x) = exp2(C2*x)
  int tid = threadIdx.x;
  int bid = blockIdx.x;
  bool isE = (bid < 512);
  int rbase = (isE ? bid : bid - 512) * 32;
  const float* in = isE ? enc : dec;
  const float* Mg = isE ? Wa : Ua;
  int hq = tid & 31, rq = tid >> 5;      // h0 = hq*4 (lanes cover 128 h), r0 = rq*4
  int h0 = hq * 4, r0 = rq * 4;
  const float* rowp = in + (size_t)(rbase + r0) * H;   // 4 rows, stride H
  const float* wp = Mg + h0;                           // weight col-block, stride H
  float4 a0{0,0,0,0}, a1{0,0,0,0}, a2{0,0,0,0}, a3{0,0,0,0};
  #pragma unroll 4
  for (int k = 0; k < 128; ++k) {
    float4 wv = *(const float4*)(wp + (size_t)k * H);  // coalesced b128
    float r0v = rowp[k];                               // 2-addr broadcast b32
    float r1v = rowp[k + H];
    float r2v = rowp[k + 2 * H];
    float r3v = rowp[k + 3 * H];
    a0.x += r0v * wv.x; a0.y += r0v * wv.y; a0.z += r0v * wv.z; a0.w += r0v * wv.w;
    a1.x += r1v * wv.x; a1.y += r1v * wv.y; a1.z += r1v * wv.z; a1.w += r1v * wv.w;
    a2.x += r2v * wv.x; a2.y += r2v * wv.y; a2.z += r2v * wv.z; a2.w += r2v * wv.w;
    a3.x += r3v * wv.x; a3.y += r3v * wv.y; a3.z += r3v * wv.z; a3.w += r3v * wv.w;
  }
  float4 e0, e1, e2, e3;
  e0.x = __builtin_amdgcn_exp2f(a0.x * C2); e0.y = __builtin_amdgcn_exp2f(a0.y * C2);
  e0.z = __builtin_amdgcn_exp2f(a0.z * C2); e0.w = __builtin_amdgcn_exp2f(a0.w * C2);
  e1.x = __builtin_amdgcn_exp2f(a1.x * C2); e1.y = __builtin_amdgcn_exp2f(a1.y * C2);
  e1.z = __builtin_amdgcn_exp2f(a1.z * C2); e1.w = __builtin_amdgcn_exp2f(a1.w * C2);
  e2.x = __builtin_amdgcn_exp2f(a2.x * C2); e2.y = __builtin_amdgcn_exp2f(a2.y * C2);
  e2.z = __builtin_amdgcn_exp2f(a2.z * C2); e2.w = __builtin_amdgcn_exp2f(a2.w * C2);
  e3.x = __builtin_amdgcn_exp2f(a3.x * C2); e3.y = __builtin_amdgcn_exp2f(a3.y * C2);
  e3.z = __builtin_amdgcn_exp2f(a3.z * C2); e3.w = __builtin_amdgcn_exp2f(a3.w * C2);
  if (isE) {
    // flip through LDS so global writes are consecutive-t coalesced
    *(float4*)&Ls[(r0 + 0) * 132 + h0] = e0;
    *(float4*)&Ls[(r0 + 1) * 132 + h0] = e1;
    *(float4*)&Ls[(r0 + 2) * 132 + h0] = e2;
    *(float4*)&Ls[(r0 + 3) * 132 + h0] = e3;
    __syncthreads();
    int b_e = rbase >> 11, t_in = rbase & 2047;
    int tb = t_in >> 6, toff = t_in & 63;
    float* dst = EgT + ((size_t)(b_e * 32 + tb) * 128) * 64 + toff;
    #pragma unroll
    for (int jj = 0; jj < 16; ++jj) {
      int idx = jj * 256 + tid;
      int r = idx & 31, k = idx >> 5;
      dst[(size_t)k * 64 + r] = Ls[r * 132 + k];
    }
  } else {
    int b_f = rbase >> 8, j_in = rbase & 255;
    float* dst = Fg + ((size_t)(b_f * TD + j_in + r0)) * H + h0;
    *(float4*)(dst + 0 * H) = e0;
    *(float4*)(dst + 1 * H) = e1;
    *(float4*)(dst + 2 * H) = e2;
    *(float4*)(dst + 3 * H) = e3;
  }
}

// ---------- kernel 2: fused scores -> softmax -> context ----------
// R9 shape (512 thr, 8 waves, 32 KB LDS) + XCD swizzle (b = bid&7 -> per-XCD L2-resident
// E/enc) + pairwise-rcp (v0/d0+v1/d1 = (v0*d1+v1*d0)*rcp(d0*d1): halves trans ops).
__global__ __launch_bounds__(512) void fused_kernel(
    const float* __restrict__ EgT, const float* __restrict__ Fg,
    const float* __restrict__ Va,  const float* __restrict__ enc,
    float* __restrict__ oute, float* __restrict__ outc) {
  __shared__ float S[4 * 2048];    // 32 KB: scores [j][t] -> e [t][4j] -> c-partials
  __shared__ float red[16];
  int tid = threadIdx.x;
  int bid = blockIdx.x;
  int b = bid & 7, jt = bid >> 3;  // consecutive ids round-robin XCDs -> XCD pinned to b
  int j0 = jt * 4;
  int lane = tid & 63, w = tid >> 6;
  const float4* vp = (const float4*)Va;
  float V1 = 0.f;                  // sum_k v_k (L1-hot broadcast loads)
  #pragma unroll
  for (int q = 0; q < 32; ++q) { float4 v = vp[q]; V1 += v.x + v.y + v.z + v.w; }

  // ---- phase 1: scores[j][t] = V1 - 2*sum_k v_k/(E[t,k]*F[j,k]+1) into LDS ----
  const float4* Fp = (const float4*)(Fg + (size_t)(b * TD + j0) * H);
  for (int it = 0; it < 4; ++it) {
    int tb = w + 8 * it;                       // 8 waves x 4 iters = 32 tb
    const float* Ep = EgT + ((size_t)(b * 32 + tb) * 128) * 64 + lane;
    float s0 = 0.f, s1 = 0.f, s2 = 0.f, s3 = 0.f;
    for (int kc = 0; kc < 16; ++kc) {          // 8 k per chunk
      const float* ep = Ep + kc * 512;
      float ek[8];
      #pragma unroll
      for (int q = 0; q < 8; ++q) ek[q] = ep[q * 64];   // imm offsets 0..1792 B
      float4 v0 = vp[kc * 2], v1 = vp[kc * 2 + 1];
      const float4* fp = Fp + kc * 2;
      #pragma unroll
      for (int j = 0; j < 4; ++j) {
        float4 f0 = fp[j * 32];                // imm offsets j*512 B
        float4 f1 = fp[j * 32 + 1];
        float d0, d1, a = 0.f;
        d0 = fmaf(ek[0], f0.x, 1.0f); d1 = fmaf(ek[1], f0.y, 1.0f);
        a += (v0.x * d1 + v0.y * d0) * __builtin_amdgcn_rcpf(d0 * d1);
        d0 = fmaf(ek[2], f0.z, 1.0f); d1 = fmaf(ek[3], f0.w, 1.0f);
        a += (v0.z * d1 + v0.w * d0) * __builtin_amdgcn_rcpf(d0 * d1);
        d0 = fmaf(ek[4], f1.x, 1.0f); d1 = fmaf(ek[5], f1.y, 1.0f);
        a += (v1.x * d1 + v1.y * d0) * __builtin_amdgcn_rcpf(d0 * d1);
        d0 = fmaf(ek[6], f1.z, 1.0f); d1 = fmaf(ek[7], f1.w, 1.0f);
        a += (v1.z * d1 + v1.w * d0) * __builtin_amdgcn_rcpf(d0 * d1);
        if (j == 0) s0 += a; else if (j == 1) s1 += a; else if (j == 2) s2 += a; else s3 += a;
      }
    }
    int t = tb * 64 + lane;
    S[0 * 2048 + t] = V1 - 2.0f * s0;          // bank = lane%32: 2-way (free)
    S[1 * 2048 + t] = V1 - 2.0f * s1;
    S[2 * 2048 + t] = V1 - 2.0f * s2;
    S[3 * 2048 + t] = V1 - 2.0f * s3;
  }
  __syncthreads();

  // ---- phase 2: softmax per j-row (2 waves per j), e -> d_out + S[t][4j] ----
  int j = w >> 1, half = w & 1;
  int tb2 = half * 1024 + lane;
  float x[16];
  #pragma unroll
  for (int q = 0; q < 16; ++q) x[q] = S[j * 2048 + tb2 + q * 64];
  float m = x[0];
  #pragma unroll
  for (int q = 1; q < 16; ++q) m = fmaxf(m, x[q]);
  #pragma unroll
  for (int off = 32; off > 0; off >>= 1) m = fmaxf(m, __shfl_xor(m, off));
  if (lane == 0) red[w] = m;
  __syncthreads();                             // also: all raw-S reads complete
  m = fmaxf(red[j * 2], red[j * 2 + 1]);
  const float L2E = 1.4426950408889634f;
  float sum = 0.f;
  #pragma unroll
  for (int q = 0; q < 16; ++q) {
    x[q] = __builtin_amdgcn_exp2f((x[q] - m) * L2E);
    sum += x[q];
  }
  #pragma unroll
  for (int off = 32; off > 0; off >>= 1) sum += __shfl_xor(sum, off);
  if (lane == 0) red[8 + w] = sum;
  __syncthreads();
  float inv = 1.0f / (red[8 + j * 2] + red[8 + j * 2 + 1]);
  float* orow = oute + (size_t)(b * TD + j0 + j) * TE;
  #pragma unroll
  for (int q = 0; q < 16; ++q) {
    float e = x[q] * inv;
    int t = tb2 + q * 64;
    orow[t] = e;                               // coalesced 256 B/instr
    S[t * 4 + j] = e;                          // S re-viewed as [t][4j]
  }
  __syncthreads();

  // ---- phase 3: c[j][h] = sum_t e[j][t]*enc[t][h]; 16 t-slices, LDS-combined ----
  int hq = tid & 31, slice = tid >> 5;         // h = hq*4; t in [slice*128, slice*128+128)
  const float* encp = enc + ((size_t)b * TE + slice * 128) * H + hq * 4;
  float4 acc0{0,0,0,0}, acc1{0,0,0,0}, acc2{0,0,0,0}, acc3{0,0,0,0};
  #pragma unroll 4
  for (int t = 0; t < 128; ++t) {
    float4 ev = *(const float4*)(encp + (size_t)t * H);          // 1 KB/wave-instr
    float4 e4 = *(const float4*)&S[(slice * 128 + t) * 4];       // b128 broadcast
    acc0.x += e4.x * ev.x; acc0.y += e4.x * ev.y; acc0.z += e4.x * ev.z; acc0.w += e4.x * ev.w;
    acc1.x += e4.y * ev.x; acc1.y += e4.y * ev.y; acc1.z += e4.y * ev.z; acc1.w += e4.y * ev.w;
    acc2.x += e4.z * ev.x; acc2.y += e4.z * ev.y; acc2.z += e4.z * ev.z; acc2.w += e4.z * ev.w;
    acc3.x += e4.w * ev.x; acc3.y += e4.w * ev.y; acc3.z += e4.w * ev.z; acc3.w += e4.w * ev.w;
  }
  __syncthreads();                             // all e-reads done; reuse S for partials
  *(float4*)&S[slice * 512 + 0 * 128 + hq * 4] = acc0;
  *(float4*)&S[slice * 512 + 1 * 128 + hq * 4] = acc1;
  *(float4*)&S[slice * 512 + 2 * 128 + hq * 4] = acc2;
  *(float4*)&S[slice * 512 + 3 * 128 + hq * 4] = acc3;
  __syncthreads();
  float r = 0.f;
  #pragma unroll
  for (int sl = 0; sl < 16; ++sl) r += S[sl * 512 + tid];        // stride-1, conflict-free
  outc[(size_t)(b * TD + j0 + (tid >> 7)) * H + (tid & 127)] = r;
}

extern "C" void kernel_launch(void* const* d_in, const int* in_sizes, int n_in,
                              void* d_out, int out_size, void* d_ws, size_t ws_size,
                              hipStream_t stream) {
  (void)in_sizes; (void)n_in; (void)out_size; (void)ws_size;
  const float* enc = (const float*)d_in[0];
  const float* dec = (const float*)d_in[1];
  const float* Wa  = (const float*)d_in[2];
  const float* Ua  = (const float*)d_in[3];
  const float* Va  = (const float*)d_in[4];

  float* ws  = (float*)d_ws;
  float* EgT = ws;                                   // 2,097,152 f32 (8 MB)  E tiled [b][tb][k][tl]
  float* Fg  = EgT + (size_t)B * TE * H;             //   262,144 f32 (1 MB)  F [b][j][k]
  float* outc = (float*)d_out;                       // c [B,TD,H] fp32
  float* oute = outc + (size_t)B * TD * H;           // e [B,TD,TE] fp32

  proj_kernel<<<dim3(576), 256, 0, stream>>>(enc, dec, Wa, Ua, EgT, Fg);
  fused_kernel<<<dim3(512), 512, 0, stream>>>(EgT, Fg, Va, enc, oute, outc);
}

// Round 12
// 166.634 us; speedup vs baseline: 1.1800x; 1.0191x over previous
//
#include <hip/hip_runtime.h>
#include <stdint.h>

#define B  8
#define TE 2048
#define TD 256
#define H  128

// ---------- kernel 1: register-tiled GEMM (R9-exact: 256 thr, 4r x 4h, b32 row loads) ----------
// E written t-tiled: EgT[b][tb][k][tl]  (tb = t>>6, tl = t&63); F row-major [b][j][k].
__global__ __launch_bounds__(256) void proj_kernel(
    const float* __restrict__ enc, const float* __restrict__ dec,
    const float* __restrict__ Wa,  const float* __restrict__ Ua,
    float* __restrict__ EgT, float* __restrict__ Fg) {
  __shared__ float Ls[32 * 132];         // 16.9 KB: E-epilogue transpose only
  const float C2 = 2.8853900817779268f;  // 2*log2(e):  exp(2x) = exp2(C2*x)
  int tid = threadIdx.x;
  int bid = blockIdx.x;
  bool isE = (bid < 512);
  int rbase = (isE ? bid : bid - 512) * 32;
  const float* in = isE ? enc : dec;
  const float* Mg = isE ? Wa : Ua;
  int hq = tid & 31, rq = tid >> 5;      // h0 = hq*4 (lanes cover 128 h), r0 = rq*4
  int h0 = hq * 4, r0 = rq * 4;
  const float* rowp = in + (size_t)(rbase + r0) * H;   // 4 rows, stride H
  const float* wp = Mg + h0;                           // weight col-block, stride H
  float4 a0{0,0,0,0}, a1{0,0,0,0}, a2{0,0,0,0}, a3{0,0,0,0};
  #pragma unroll 4
  for (int k = 0; k < 128; ++k) {
    float4 wv = *(const float4*)(wp + (size_t)k * H);  // coalesced b128
    float r0v = rowp[k];                               // 2-addr broadcast b32
    float r1v = rowp[k + H];
    float r2v = rowp[k + 2 * H];
    float r3v = rowp[k + 3 * H];
    a0.x += r0v * wv.x; a0.y += r0v * wv.y; a0.z += r0v * wv.z; a0.w += r0v * wv.w;
    a1.x += r1v * wv.x; a1.y += r1v * wv.y; a1.z += r1v * wv.z; a1.w += r1v * wv.w;
    a2.x += r2v * wv.x; a2.y += r2v * wv.y; a2.z += r2v * wv.z; a2.w += r2v * wv.w;
    a3.x += r3v * wv.x; a3.y += r3v * wv.y; a3.z += r3v * wv.z; a3.w += r3v * wv.w;
  }
  float4 e0, e1, e2, e3;
  e0.x = __builtin_amdgcn_exp2f(a0.x * C2); e0.y = __builtin_amdgcn_exp2f(a0.y * C2);
  e0.z = __builtin_amdgcn_exp2f(a0.z * C2); e0.w = __builtin_amdgcn_exp2f(a0.w * C2);
  e1.x = __builtin_amdgcn_exp2f(a1.x * C2); e1.y = __builtin_amdgcn_exp2f(a1.y * C2);
  e1.z = __builtin_amdgcn_exp2f(a1.z * C2); e1.w = __builtin_amdgcn_exp2f(a1.w * C2);
  e2.x = __builtin_amdgcn_exp2f(a2.x * C2); e2.y = __builtin_amdgcn_exp2f(a2.y * C2);
  e2.z = __builtin_amdgcn_exp2f(a2.z * C2); e2.w = __builtin_amdgcn_exp2f(a2.w * C2);
  e3.x = __builtin_amdgcn_exp2f(a3.x * C2); e3.y = __builtin_amdgcn_exp2f(a3.y * C2);
  e3.z = __builtin_amdgcn_exp2f(a3.z * C2); e3.w = __builtin_amdgcn_exp2f(a3.w * C2);
  if (isE) {
    // flip through LDS so global writes are consecutive-t coalesced
    *(float4*)&Ls[(r0 + 0) * 132 + h0] = e0;
    *(float4*)&Ls[(r0 + 1) * 132 + h0] = e1;
    *(float4*)&Ls[(r0 + 2) * 132 + h0] = e2;
    *(float4*)&Ls[(r0 + 3) * 132 + h0] = e3;
    __syncthreads();
    int b_e = rbase >> 11, t_in = rbase & 2047;
    int tb = t_in >> 6, toff = t_in & 63;
    float* dst = EgT + ((size_t)(b_e * 32 + tb) * 128) * 64 + toff;
    #pragma unroll
    for (int jj = 0; jj < 16; ++jj) {
      int idx = jj * 256 + tid;
      int r = idx & 31, k = idx >> 5;
      dst[(size_t)k * 64 + r] = Ls[r * 132 + k];
    }
  } else {
    int b_f = rbase >> 8, j_in = rbase & 255;
    float* dst = Fg + ((size_t)(b_f * TD + j_in + r0)) * H + h0;
    *(float4*)(dst + 0 * H) = e0;
    *(float4*)(dst + 1 * H) = e1;
    *(float4*)(dst + 2 * H) = e2;
    *(float4*)(dst + 3 * H) = e3;
  }
}

// ---------- kernel 2: fused scores -> softmax -> context ----------
// XCD swizzle (b = bid&7). Phase 1 restructured: kc-outer / it-inner, F hoisted per kc
// (4x fewer F loads), 40 independent loads per kc vs 1280 VALU cyc -> latency covered.
__global__ __launch_bounds__(512, 4) void fused_kernel(
    const float* __restrict__ EgT, const float* __restrict__ Fg,
    const float* __restrict__ Va,  const float* __restrict__ enc,
    float* __restrict__ oute, float* __restrict__ outc) {
  __shared__ float S[4 * 2048];    // 32 KB: scores [j][t] -> e [t][4j] -> c-partials
  __shared__ float red[16];
  int tid = threadIdx.x;
  int bid = blockIdx.x;
  int b = bid & 7, jt = bid >> 3;  // consecutive ids round-robin XCDs -> XCD pinned to b
  int j0 = jt * 4;
  int lane = tid & 63, w = tid >> 6;
  const float4* vp = (const float4*)Va;
  float V1 = 0.f;                  // sum_k v_k (L1-hot broadcast loads)
  #pragma unroll
  for (int q = 0; q < 32; ++q) { float4 v = vp[q]; V1 += v.x + v.y + v.z + v.w; }

  // ---- phase 1: scores[j][t] = V1 - 2*sum_k v_k/(E[t,k]*F[j,k]+1) into LDS ----
  const float4* Fp = (const float4*)(Fg + (size_t)(b * TD + j0) * H);
  const float* Ep[4];
  #pragma unroll
  for (int it = 0; it < 4; ++it)
    Ep[it] = EgT + ((size_t)(b * 32 + w + 8 * it) * 128) * 64 + lane;
  float s[4][4];
  #pragma unroll
  for (int it = 0; it < 4; ++it)
    #pragma unroll
    for (int j = 0; j < 4; ++j) s[it][j] = 0.f;

  for (int kc = 0; kc < 16; ++kc) {          // 8 k per chunk
    float4 f0[4], f1[4];
    const float4* fpc = Fp + kc * 2;
    #pragma unroll
    for (int j = 0; j < 4; ++j) {            // 8 b128 F loads, once per kc
      f0[j] = fpc[j * 32];
      f1[j] = fpc[j * 32 + 1];
    }
    float4 v0 = vp[kc * 2], v1 = vp[kc * 2 + 1];
    #pragma unroll
    for (int it = 0; it < 4; ++it) {
      const float* ep = Ep[it] + kc * 512;
      float ek[8];
      #pragma unroll
      for (int q = 0; q < 8; ++q) ek[q] = ep[q * 64];   // 8 b32, imm offsets
      #pragma unroll
      for (int j = 0; j < 4; ++j) {
        float d0, d1, a = 0.f;
        d0 = fmaf(ek[0], f0[j].x, 1.0f); d1 = fmaf(ek[1], f0[j].y, 1.0f);
        a += (v0.x * d1 + v0.y * d0) * __builtin_amdgcn_rcpf(d0 * d1);
        d0 = fmaf(ek[2], f0[j].z, 1.0f); d1 = fmaf(ek[3], f0[j].w, 1.0f);
        a += (v0.z * d1 + v0.w * d0) * __builtin_amdgcn_rcpf(d0 * d1);
        d0 = fmaf(ek[4], f1[j].x, 1.0f); d1 = fmaf(ek[5], f1[j].y, 1.0f);
        a += (v1.x * d1 + v1.y * d0) * __builtin_amdgcn_rcpf(d0 * d1);
        d0 = fmaf(ek[6], f1[j].z, 1.0f); d1 = fmaf(ek[7], f1[j].w, 1.0f);
        a += (v1.z * d1 + v1.w * d0) * __builtin_amdgcn_rcpf(d0 * d1);
        s[it][j] += a;
      }
    }
  }
  #pragma unroll
  for (int it = 0; it < 4; ++it) {
    int t = (w + 8 * it) * 64 + lane;
    S[0 * 2048 + t] = V1 - 2.0f * s[it][0];  // bank = lane%32: 2-way (free)
    S[1 * 2048 + t] = V1 - 2.0f * s[it][1];
    S[2 * 2048 + t] = V1 - 2.0f * s[it][2];
    S[3 * 2048 + t] = V1 - 2.0f * s[it][3];
  }
  __syncthreads();

  // ---- phase 2: softmax per j-row (2 waves per j), e -> d_out + S[t][4j] ----
  int j = w >> 1, half = w & 1;
  int tb2 = half * 1024 + lane;
  float x[16];
  #pragma unroll
  for (int q = 0; q < 16; ++q) x[q] = S[j * 2048 + tb2 + q * 64];
  float m = x[0];
  #pragma unroll
  for (int q = 1; q < 16; ++q) m = fmaxf(m, x[q]);
  #pragma unroll
  for (int off = 32; off > 0; off >>= 1) m = fmaxf(m, __shfl_xor(m, off));
  if (lane == 0) red[w] = m;
  __syncthreads();                             // also: all raw-S reads complete
  m = fmaxf(red[j * 2], red[j * 2 + 1]);
  const float L2E = 1.4426950408889634f;
  float sum = 0.f;
  #pragma unroll
  for (int q = 0; q < 16; ++q) {
    x[q] = __builtin_amdgcn_exp2f((x[q] - m) * L2E);
    sum += x[q];
  }
  #pragma unroll
  for (int off = 32; off > 0; off >>= 1) sum += __shfl_xor(sum, off);
  if (lane == 0) red[8 + w] = sum;
  __syncthreads();
  float inv = 1.0f / (red[8 + j * 2] + red[8 + j * 2 + 1]);
  float* orow = oute + (size_t)(b * TD + j0 + j) * TE;
  #pragma unroll
  for (int q = 0; q < 16; ++q) {
    float e = x[q] * inv;
    int t = tb2 + q * 64;
    orow[t] = e;                               // coalesced 256 B/instr
    S[t * 4 + j] = e;                          // S re-viewed as [t][4j]
  }
  __syncthreads();

  // ---- phase 3: c[j][h] = sum_t e[j][t]*enc[t][h]; 16 t-slices, LDS-combined ----
  int hq = tid & 31, slice = tid >> 5;         // h = hq*4; t in [slice*128, slice*128+128)
  const float* encp = enc + ((size_t)b * TE + slice * 128) * H + hq * 4;
  float4 acc0{0,0,0,0}, acc1{0,0,0,0}, acc2{0,0,0,0}, acc3{0,0,0,0};
  #pragma unroll 4
  for (int t = 0; t < 128; ++t) {
    float4 ev = *(const float4*)(encp + (size_t)t * H);          // 1 KB/wave-instr
    float4 e4 = *(const float4*)&S[(slice * 128 + t) * 4];       // b128 broadcast
    acc0.x += e4.x * ev.x; acc0.y += e4.x * ev.y; acc0.z += e4.x * ev.z; acc0.w += e4.x * ev.w;
    acc1.x += e4.y * ev.x; acc1.y += e4.y * ev.y; acc1.z += e4.y * ev.z; acc1.w += e4.y * ev.w;
    acc2.x += e4.z * ev.x; acc2.y += e4.z * ev.y; acc2.z += e4.z * ev.z; acc2.w += e4.z * ev.w;
    acc3.x += e4.w * ev.x; acc3.y += e4.w * ev.y; acc3.z += e4.w * ev.z; acc3.w += e4.w * ev.w;
  }
  __syncthreads();                             // all e-reads done; reuse S for partials
  *(float4*)&S[slice * 512 + 0 * 128 + hq * 4] = acc0;
  *(float4*)&S[slice * 512 + 1 * 128 + hq * 4] = acc1;
  *(float4*)&S[slice * 512 + 2 * 128 + hq * 4] = acc2;
  *(float4*)&S[slice * 512 + 3 * 128 + hq * 4] = acc3;
  __syncthreads();
  float r = 0.f;
  #pragma unroll
  for (int sl = 0; sl < 16; ++sl) r += S[sl * 512 + tid];        // stride-1, conflict-free
  outc[(size_t)(b * TD + j0 + (tid >> 7)) * H + (tid & 127)] = r;
}

extern "C" void kernel_launch(void* const* d_in, const int* in_sizes, int n_in,
                              void* d_out, int out_size, void* d_ws, size_t ws_size,
                              hipStream_t stream) {
  (void)in_sizes; (void)n_in; (void)out_size; (void)ws_size;
  const float* enc = (const float*)d_in[0];
  const float* dec = (const float*)d_in[1];
  const float* Wa  = (const float*)d_in[2];
  const float* Ua  = (const float*)d_in[3];
  const float* Va  = (const float*)d_in[4];

  float* ws  = (float*)d_ws;
  float* EgT = ws;                                   // 2,097,152 f32 (8 MB)  E tiled [b][tb][k][tl]
  float* Fg  = EgT + (size_t)B * TE * H;             //   262,144 f32 (1 MB)  F [b][j][k]
  float* outc = (float*)d_out;                       // c [B,TD,H] fp32
  float* oute = outc + (size_t)B * TD * H;           // e [B,TD,TE] fp32

  proj_kernel<<<dim3(576), 256, 0, stream>>>(enc, dec, Wa, Ua, EgT, Fg);
  fused_kernel<<<dim3(512), 512, 0, stream>>>(EgT, Fg, Va, enc, oute, outc);
}